// Round 4
// baseline (159.303 us; speedup 1.0000x reference)
//
#include <hip/hip_runtime.h>

#define NEGV (-1e30f)   // reference's NEG for padded positions

// One WAVE per row (256-thread block = 4 rows). L=512 -> 8 elements/lane.
// No LDS, no __syncthreads: wave-local butterfly max, per-lane local suffix
// over 8 regs + wave suffix-scan of lane totals. Finalize fused via
// threadfence + arrival counter: last wave reduces part[] -> out.
__global__ __launch_bounds__(256) void listnet_fused_kernel(
    const float* __restrict__ scores,
    const int*   __restrict__ seqs,
    float2*      __restrict__ part,   // [B] per-row (ll, used)
    int*         __restrict__ counter,// zeroed by memset each launch
    float*       __restrict__ out,
    int N, int L, int B)
{
    const int lane = threadIdx.x & 63;
    const int wv   = threadIdx.x >> 6;
    const int row  = blockIdx.x * 4 + wv;
    if (row >= B) return;

    const float* srow  = scores + (size_t)row * N;
    const int4*  irow4 = (const int4*)(seqs + (size_t)row * L);

    // lane owns positions [8*lane .. 8*lane+7]: two int4 idx loads
    int4 ia = irow4[lane * 2];
    int4 ib = irow4[lane * 2 + 1];
    int idx[8] = {ia.x, ia.y, ia.z, ia.w, ib.x, ib.y, ib.z, ib.w};

    float x[8];
    float mloc = NEGV;
    #pragma unroll
    for (int j = 0; j < 8; ++j) {
        bool v = (idx[j] != -1);
        int  c = min(max(idx[j], 0), N - 1);
        float g = srow[c];                       // 8 gathers in flight
        g = isnan(g) ? 0.f : fminf(fmaxf(g, -1e6f), 1e6f);  // torch_sanitize
        x[j] = v ? g : NEGV;
        mloc = fmaxf(mloc, x[j]);
    }

    // wave max (butterfly -> all lanes)
    float M = mloc;
    #pragma unroll
    for (int off = 32; off; off >>= 1)
        M = fmaxf(M, __shfl_xor(M, off, 64));

    // per-lane suffix sums of exp(x - M)  (padded -> exactly 0)
    float suf[8];
    float run = 0.f;
    #pragma unroll
    for (int j = 7; j >= 0; --j) {
        run += __expf(x[j] - M);
        suf[j] = run;
    }

    // wave inclusive suffix-scan of lane totals
    float S = run;
    #pragma unroll
    for (int off = 1; off < 64; off <<= 1) {
        float o = __shfl_down(S, off, 64);
        S += (lane + off < 64) ? o : 0.f;
    }
    float A = __shfl_down(S, 1, 64);   // suffix strictly after this lane
    if (lane == 63) A = 0.f;

    // log-likelihood contributions
    float ll = 0.f;
    #pragma unroll
    for (int j = 0; j < 8; ++j) {
        if (idx[j] != -1)
            ll += x[j] - (M + __logf(suf[j] + A));
    }
    // wave reduce (lane 0 complete)
    #pragma unroll
    for (int off = 32; off; off >>= 1)
        ll += __shfl_down(ll, off, 64);

    int old = 0;
    if (lane == 0) {
        bool used = (M > -1e29f);
        float2 r;
        r.x = used ? ll : 0.f;
        r.y = used ? 1.f : 0.f;
        part[row] = r;
        __threadfence();                       // make part[row] device-visible
        old = atomicAdd(counter, 1);
    }
    old = __shfl(old, 0, 64);

    if (old == B - 1) {                        // last-arriving wave finalizes
        __threadfence();
        const volatile float2* vp = (const volatile float2*)part;
        float tot = 0.f, cnt = 0.f;
        for (int i = lane; i < B; i += 64) {
            float2 p; p.x = vp[i].x; p.y = vp[i].y;
            tot += p.x;
            cnt += p.y;
        }
        #pragma unroll
        for (int off = 32; off; off >>= 1) {
            tot += __shfl_down(tot, off, 64);
            cnt += __shfl_down(cnt, off, 64);
        }
        if (lane == 0)
            out[0] = (cnt > 0.f) ? (-tot / cnt) : 0.f;
    }
}

extern "C" void kernel_launch(void* const* d_in, const int* in_sizes, int n_in,
                              void* d_out, int out_size, void* d_ws, size_t ws_size,
                              hipStream_t stream) {
    const float* scores = (const float*)d_in[0];
    const int*   seqs   = (const int*)d_in[1];
    float*       out    = (float*)d_out;

    const int L = 512;
    const int B = in_sizes[1] / L;          // 2048
    const int N = in_sizes[0] / B;          // 8192

    float2* part    = (float2*)d_ws;                         // 16 KB
    int*    counter = (int*)((char*)d_ws + (size_t)B * sizeof(float2));

    hipMemsetAsync(counter, 0, sizeof(int), stream);         // arrival counter
    listnet_fused_kernel<<<(B + 3) / 4, 256, 0, stream>>>(
        scores, seqs, part, counter, out, N, L, B);
}

// Round 5
// 101.651 us; speedup vs baseline: 1.5672x; 1.5672x over previous
//
#include <hip/hip_runtime.h>

#define NEGV (-1e30f)   // reference's NEG for padded positions

// One WAVE per row (256-thread block = 4 independent rows). L=512 -> 8/lane.
// No LDS, no __syncthreads, no atomics: wave butterfly max, per-lane suffix
// over 8 regs + wave suffix-scan of lane totals, contention-free part[] store.
__global__ __launch_bounds__(256) void listnet_row_kernel(
    const float* __restrict__ scores,
    const int*   __restrict__ seqs,
    float2*      __restrict__ part,   // [B] per-row (ll, used)
    int N, int L, int B)
{
    const int lane = threadIdx.x & 63;
    const int wv   = threadIdx.x >> 6;
    const int row  = blockIdx.x * 4 + wv;
    if (row >= B) return;

    const float* srow  = scores + (size_t)row * N;
    const int4*  irow4 = (const int4*)(seqs + (size_t)row * L);

    // lane owns positions [8*lane .. 8*lane+7]: two int4 idx loads
    int4 ia = irow4[lane * 2];
    int4 ib = irow4[lane * 2 + 1];
    int idx[8] = {ia.x, ia.y, ia.z, ia.w, ib.x, ib.y, ib.z, ib.w};

    float x[8];
    float mloc = NEGV;
    #pragma unroll
    for (int j = 0; j < 8; ++j) {
        bool v = (idx[j] != -1);
        int  c = min(max(idx[j], 0), N - 1);
        float g = srow[c];                       // 8 gathers in flight
        g = isnan(g) ? 0.f : fminf(fmaxf(g, -1e6f), 1e6f);  // torch_sanitize
        x[j] = v ? g : NEGV;
        mloc = fmaxf(mloc, x[j]);
    }

    // wave max (butterfly -> all lanes)
    float M = mloc;
    #pragma unroll
    for (int off = 32; off; off >>= 1)
        M = fmaxf(M, __shfl_xor(M, off, 64));

    // per-lane suffix sums of exp(x - M)  (padded -> exactly 0)
    float suf[8];
    float run = 0.f;
    #pragma unroll
    for (int j = 7; j >= 0; --j) {
        run += __expf(x[j] - M);
        suf[j] = run;
    }

    // wave inclusive suffix-scan of lane totals
    float S = run;
    #pragma unroll
    for (int off = 1; off < 64; off <<= 1) {
        float o = __shfl_down(S, off, 64);
        S += (lane + off < 64) ? o : 0.f;
    }
    float A = __shfl_down(S, 1, 64);   // suffix strictly after this lane
    if (lane == 63) A = 0.f;

    // log-likelihood contributions
    float ll = 0.f;
    #pragma unroll
    for (int j = 0; j < 8; ++j) {
        if (idx[j] != -1)
            ll += x[j] - (M + __logf(suf[j] + A));
    }
    // wave reduce (lane 0 complete)
    #pragma unroll
    for (int off = 32; off; off >>= 1)
        ll += __shfl_down(ll, off, 64);

    if (lane == 0) {
        bool used = (M > -1e29f);
        float2 r;
        r.x = used ? ll : 0.f;
        r.y = used ? 1.f : 0.f;
        part[row] = r;                 // contention-free per-row store
    }
}

// Single-wave reduction over B per-row partials -> scalar loss.
__global__ __launch_bounds__(64) void listnet_finalize_kernel(
    const float2* __restrict__ part, float* __restrict__ out, int B)
{
    const int t = threadIdx.x;          // 0..63, one wave
    float tot = 0.f, cnt = 0.f;
    for (int i = t; i < B; i += 64) {
        float2 p = part[i];
        tot += p.x;
        cnt += p.y;
    }
    #pragma unroll
    for (int off = 32; off; off >>= 1) {
        tot += __shfl_down(tot, off, 64);
        cnt += __shfl_down(cnt, off, 64);
    }
    if (t == 0)
        out[0] = (cnt > 0.f) ? (-tot / cnt) : 0.f;
}

extern "C" void kernel_launch(void* const* d_in, const int* in_sizes, int n_in,
                              void* d_out, int out_size, void* d_ws, size_t ws_size,
                              hipStream_t stream) {
    const float* scores = (const float*)d_in[0];
    const int*   seqs   = (const int*)d_in[1];
    float*       out    = (float*)d_out;
    float2*      part   = (float2*)d_ws;

    const int L = 512;
    const int B = in_sizes[1] / L;          // 2048
    const int N = in_sizes[0] / B;          // 8192

    listnet_row_kernel<<<(B + 3) / 4, 256, 0, stream>>>(scores, seqs, part, N, L, B);
    listnet_finalize_kernel<<<1, 64, 0, stream>>>(part, out, B);
}

// Round 6
// 96.076 us; speedup vs baseline: 1.6581x; 1.0580x over previous
//
#include <hip/hip_runtime.h>

#define NEGV (-1e30f)   // reference's NEG for padded positions
#define IDM  (-1e38f)   // logsumexp identity max (finite to avoid inf-inf NaN)

struct LSE { float m, s; };

// combine two (max, sum-of-exp) pairs: logsumexp merge. Associative.
__device__ __forceinline__ LSE lse_comb(LSE a, LSE b) {
    float M = fmaxf(a.m, b.m);
    LSE r;
    r.m = M;
    r.s = a.s * __expf(a.m - M) + b.s * __expf(b.m - M);
    return r;
}

// One block (256 threads) per row. L=512 -> 2 elements/thread.
// Suffix logsumexp = reverse cumlogsumexp via wave suffix-scan + LDS wave combine.
// Result: part[b] = (row_ll or 0, used ? 1 : 0) -- contention-free store.
// NOTE (session finding, R1/R4): NEVER put a same-address atomic on the
// critical path here — 2048 serialized RMWs cost ~80 µs on gfx950.
__global__ __launch_bounds__(256) void listnet_row_kernel(
    const float* __restrict__ scores,
    const int*   __restrict__ seqs,
    float2*      __restrict__ part,  // [B] per-row partials
    int N, int L)
{
    const int b = blockIdx.x;
    const float* srow = scores + (size_t)b * N;
    const int2*  irow = (const int2*)(seqs + (size_t)b * L);

    const int t    = threadIdx.x;   // 0..255
    const int lane = t & 63;
    const int wv   = t >> 6;        // 0..3

    // elements 2t (e0) and 2t+1 (e1), coalesced 8B/lane index load
    int2 ii = irow[t];
    bool v0 = (ii.x != -1), v1 = (ii.y != -1);
    int  c0 = min(max(ii.x, 0), N - 1);
    int  c1 = min(max(ii.y, 0), N - 1);
    float g0 = srow[c0];
    float g1 = srow[c1];
    // torch_sanitize: nan->0, +inf->1e6, -inf->-1e6
    g0 = isnan(g0) ? 0.f : fminf(fmaxf(g0, -1e6f), 1e6f);
    g1 = isnan(g1) ? 0.f : fminf(fmaxf(g1, -1e6f), 1e6f);
    float x0 = v0 ? g0 : NEGV;
    float x1 = v1 ? g1 : NEGV;

    // per-thread pair over its 2 elements
    float M2 = fmaxf(x0, x1);
    LSE inc; inc.m = M2; inc.s = __expf(x0 - M2) + __expf(x1 - M2);

    // wave-level inclusive SUFFIX scan (Hillis-Steele, combine of lanes [i..63])
    #pragma unroll
    for (int off = 1; off < 64; off <<= 1) {
        float om = __shfl_down(inc.m, off, 64);
        float os = __shfl_down(inc.s, off, 64);
        if (lane + off < 64) { LSE o; o.m = om; o.s = os; inc = lse_comb(inc, o); }
    }

    // wave totals (lane 0 holds combine of whole wave) -> LDS
    __shared__ float wm[4], wsv[4];
    if (lane == 0) { wm[wv] = inc.m; wsv[wv] = inc.s; }

    // thread-exclusive within wave = inclusive of lane+1 (identity for lane 63)
    float em = __shfl_down(inc.m, 1, 64);
    float es = __shfl_down(inc.s, 1, 64);
    LSE exc;
    if (lane < 63) { exc.m = em; exc.s = es; }
    else           { exc.m = IDM; exc.s = 0.f; }

    __syncthreads();

    // combine totals of higher waves (elements after this wave's range)
    LSE above; above.m = IDM; above.s = 0.f;
    #pragma unroll
    for (int w2 = 1; w2 < 4; ++w2) {
        if (wv + w2 < 4) { LSE o; o.m = wm[wv + w2]; o.s = wsv[wv + w2]; above = lse_comb(above, o); }
    }
    LSE e_thr = lse_comb(exc, above);   // suffix strictly after element e1

    // per-element log-denominators (suffix including self)
    LSE p1; p1.m = x1; p1.s = 1.f;
    LSE s1 = lse_comb(p1, e_thr);
    float d1 = s1.m + __logf(s1.s);
    LSE p0; p0.m = x0; p0.s = 1.f;
    LSE s0 = lse_comb(p0, s1);
    float d0 = s0.m + __logf(s0.s);

    float ll  = (v1 ? (x1 - d1) : 0.f) + (v0 ? (x0 - d0) : 0.f);
    int   cnt = (int)v0 + (int)v1;

    // block reduction of ll and valid-count
    #pragma unroll
    for (int off = 32; off > 0; off >>= 1) {
        ll  += __shfl_down(ll,  off, 64);
        cnt += __shfl_down(cnt, off, 64);
    }
    __shared__ float lsum[4];
    __shared__ int   csum[4];
    if (lane == 0) { lsum[wv] = ll; csum[wv] = cnt; }
    __syncthreads();
    if (t == 0) {
        float rowll = lsum[0] + lsum[1] + lsum[2] + lsum[3];
        int   rowc  = csum[0] + csum[1] + csum[2] + csum[3];
        float2 r;
        r.x = (rowc > 0) ? rowll : 0.f;
        r.y = (rowc > 0) ? 1.f   : 0.f;
        part[b] = r;                    // contention-free per-block store
    }
}

// Single-block reduction over B per-row partials -> scalar loss.
__global__ __launch_bounds__(256) void listnet_finalize_kernel(
    const float2* __restrict__ part, float* __restrict__ out, int B)
{
    const int t    = threadIdx.x;
    const int lane = t & 63;
    const int wv   = t >> 6;

    float tot = 0.f, cnt = 0.f;
    for (int i = t; i < B; i += 256) {
        float2 p = part[i];
        tot += p.x;
        cnt += p.y;
    }
    #pragma unroll
    for (int off = 32; off > 0; off >>= 1) {
        tot += __shfl_down(tot, off, 64);
        cnt += __shfl_down(cnt, off, 64);
    }
    __shared__ float ts[4], cs[4];
    if (lane == 0) { ts[wv] = tot; cs[wv] = cnt; }
    __syncthreads();
    if (t == 0) {
        float T = ts[0] + ts[1] + ts[2] + ts[3];
        float C = cs[0] + cs[1] + cs[2] + cs[3];
        out[0] = (C > 0.f) ? (-T / C) : 0.f;
    }
}

extern "C" void kernel_launch(void* const* d_in, const int* in_sizes, int n_in,
                              void* d_out, int out_size, void* d_ws, size_t ws_size,
                              hipStream_t stream) {
    const float* scores = (const float*)d_in[0];
    const int*   seqs   = (const int*)d_in[1];
    float*       out    = (float*)d_out;
    float2*      part   = (float2*)d_ws;

    const int L = 512;
    const int B = in_sizes[1] / L;          // 2048
    const int N = in_sizes[0] / B;          // 8192

    listnet_row_kernel<<<B, 256, 0, stream>>>(scores, seqs, part, N, L);
    listnet_finalize_kernel<<<1, 256, 0, stream>>>(part, out, B);
}